// Round 5
// baseline (262.992 us; speedup 1.0000x reference)
//
#include <hip/hip_runtime.h>
#include <cstdint>
#include <cmath>

#define LN_EPS 1e-6f

// ---- workspace layout (float offsets) ----
#define O_QP    0u                     // qpart [16][3072]
#define O_Q     73728u                 // [3072] scaled q
#define O_WK    76800u                 // wk_eff [768][12]
#define O_PLOG  86016u                 // partial logits [2][96][4096]
#define O_PHP   1658880u               // ph partials [32][96][768]
#define N_SC    32
#define O_CTXP  4091904u               // ctx partials [24][8][3072]
#define N_CCH   24
#define O_OUTP  4681728u               // out partials [96][8][768]
#define N_ICH   96
// end: 5271552 floats = 21.1 MB (ws is ~384 MiB)

__device__ __forceinline__ float waveReduceSum(float v) {
#pragma unroll
    for (int o = 32; o >= 1; o >>= 1) v += __shfl_xor(v, o, 64);
    return v;
}
__device__ __forceinline__ float waveReduceMax(float v) {
#pragma unroll
    for (int o = 32; o >= 1; o >>= 1) v = fmaxf(v, __shfl_xor(v, o, 64));
    return v;
}

// Workgroup barrier without vmcnt drain (LDS visibility only).
__device__ __forceinline__ void block_sync_lds() {
    asm volatile("s_waitcnt lgkmcnt(0)" ::: "memory");
    __builtin_amdgcn_s_barrier();
    asm volatile("" ::: "memory");
}

// K1a: qpart[16][3072] over 768 blocks (48 col-tiles x 16 row-groups of 48 rows).
__global__ __launch_bounds__(256) void k1a_qpart(const float* __restrict__ pq,
                                                 const float* __restrict__ Wq,
                                                 float* __restrict__ ws) {
    __shared__ float sh[4][64];
    int bid = blockIdx.x;              // 768
    int ctile = bid % 48, rg = bid / 48;
    int tid = threadIdx.x;
    int l = tid & 63, sub = tid >> 6;
    int col = ctile * 64 + l;
    const float* wq = Wq + (size_t)(rg * 48 + sub * 12) * 3072 + col;
    const float* pr = pq + rg * 48 + sub * 12;
    float acc = 0.f;
#pragma unroll
    for (int i = 0; i < 12; ++i) acc += pr[i] * wq[(size_t)i * 3072];
    sh[sub][l] = acc;
    __syncthreads();
    if (tid < 64) {
        int c2 = ctile * 64 + tid;
        ws[O_QP + rg * 3072 + c2] = sh[0][tid] + sh[1][tid] + sh[2][tid] + sh[3][tid];
    }
}

// K1b: reduce 16 qparts + bias + softplus scale (12 blocks).
__global__ __launch_bounds__(256) void k1b_qreduce(const float* __restrict__ bq,
                                                   const float* __restrict__ pds,
                                                   float* __restrict__ ws) {
    int j = blockIdx.x * 256 + threadIdx.x;   // < 3072
    float a = bq[j];
#pragma unroll
    for (int rg = 0; rg < 16; ++rg) a += ws[O_QP + rg * 3072 + j];
    float x = pds[j & 255];
    float sp = (x > 20.f) ? x : log1pf(expf(x));
    ws[O_Q + j] = a * (1.442695041f / 16.0f) * sp;
}

// K2: wk_eff[c][h] = sum_d Wk[c, h*256+d]*q[h,d]
// (bk folds to a per-row softmax-invariant constant -> dropped)
__global__ __launch_bounds__(256) void k2_wkeff(const float* __restrict__ Wk,
                                                float* __restrict__ ws) {
    int c = blockIdx.x;                // 768
    int tid = threadIdx.x;
    int w = tid >> 6, lane = tid & 63;
    const float4* wk = reinterpret_cast<const float4*>(Wk + (size_t)c * 3072);
    const float4* qv = reinterpret_cast<const float4*>(ws + O_Q);
#pragma unroll
    for (int i = 0; i < 3; ++i) {
        int h = w * 3 + i;
        float4 a = wk[h * 64 + lane];
        float4 b = qv[h * 64 + lane];
        float d = a.x * b.x + a.y * b.y + a.z * b.z + a.w * b.w;
        d = waveReduceSum(d);
        if (lane == 0) ws[O_WK + c * 12 + h] = d;
    }
}

// K3: partial logits. block = (b, s-tile of 64 rows, c-HALF of 384).
// 8 chunks of 48 c, depth-2 register prefetch, raw-barrier sync (no vmcnt drain),
// wk via readfirstlane-uniform scalar loads. Verified round 2.
__global__ __launch_bounds__(256) void k3_logits(const float* __restrict__ hidden,
                                                 const float* __restrict__ wk,
                                                 float* __restrict__ plog) {
    __shared__ float4 tile4[2][768];   // 2 x 12 KB: [buf][r*12 + (j^(r&3))]
    int blk = blockIdx.x;              // 1024 = 8 b * 64 stiles * 2 halves
    int q2 = blk & 1;
    int st = (blk >> 1) & 63;
    int b = blk >> 7;
    int s0 = st * 64;
    const float* hb = hidden + (size_t)(b * 4096 + s0) * 768 + q2 * 384;
    int tid = threadIdx.x;
    int w = tid >> 6, lane = tid & 63;
    int rr[3], jj[3];
#pragma unroll
    for (int t = 0; t < 3; ++t) {
        int idx = t * 256 + tid;       // < 768
        rr[t] = idx / 12;
        jj[t] = idx % 12;
    }
    float4 v0[3], v1[3];
#pragma unroll
    for (int t = 0; t < 3; ++t)
        v0[t] = *reinterpret_cast<const float4*>(hb + rr[t] * 768 + jj[t] * 4);
#pragma unroll
    for (int t = 0; t < 3; ++t)
        v1[t] = *reinterpret_cast<const float4*>(hb + rr[t] * 768 + 48 + jj[t] * 4);

    float acc[12];
#pragma unroll
    for (int h = 0; h < 12; ++h) acc[h] = 0.f;

    auto step = [&](float4 (&v)[3], float4* buf, int ck) {
#pragma unroll
        for (int t = 0; t < 3; ++t)
            buf[rr[t] * 12 + (jj[t] ^ (rr[t] & 3))] = v[t];
        if (ck < 6) {
#pragma unroll
            for (int t = 0; t < 3; ++t)
                v[t] = *reinterpret_cast<const float4*>(hb + rr[t] * 768 + (ck + 2) * 48 + jj[t] * 4);
        }
        int wkoff = __builtin_amdgcn_readfirstlane((q2 * 384 + ck * 48 + (tid >> 6) * 12) * 12);
        const float* wr = wk + wkoff;
        block_sync_lds();
#pragma unroll
        for (int j2 = 0; j2 < 3; ++j2) {
            int jcol = w * 3 + j2;
            float4 x = buf[lane * 12 + (jcol ^ (lane & 3))];
            const float* wv = wr + j2 * 48;     // 4 c x 12 h, uniform address
            float xc[4] = {x.x, x.y, x.z, x.w};
#pragma unroll
            for (int cc = 0; cc < 4; ++cc) {
                const float* wc = wv + cc * 12;
#pragma unroll
                for (int h = 0; h < 12; ++h)
                    acc[h] += xc[cc] * wc[h];
            }
        }
    };
#pragma unroll
    for (int ck2 = 0; ck2 < 8; ck2 += 2) {
        step(v0, tile4[0], ck2);
        step(v1, tile4[1], ck2 + 1);
    }
    float* red = reinterpret_cast<float*>(tile4);
#pragma unroll
    for (int h = 0; h < 12; ++h) red[(w * 12 + h) * 64 + lane] = acc[h];
    __syncthreads();
    for (int idx = tid; idx < 768; idx += 256) {
        int h = idx / 64, r2 = idx & 63;
        float vv = red[(0 + h) * 64 + r2] + red[(12 + h) * 64 + r2] +
                   red[(24 + h) * 64 + r2] + red[(36 + h) * 64 + r2];
        plog[(size_t)q2 * 393216 + (size_t)(b * 12 + h) * 4096 + s0 + r2] = vv;
    }
}

// K4: softmax over s=4096, 1024 threads/block (1 float4 per thread).
// attn_t dropped this round: its 4B-scatter writes cost ~32MB of amplified HBM
// write traffic (mega-round WRITE_SIZE evidence). k5 reads attn directly.
__global__ __launch_bounds__(1024) void k4_softmax(const float* __restrict__ ws,
                                                   float* __restrict__ attn) {
    __shared__ float sh[32];           // [0..15] max, [16..31] sum
    int row = blockIdx.x;              // 96 = 8*12
    const float4* p0 = reinterpret_cast<const float4*>(ws + O_PLOG + (size_t)row * 4096);
    const float4* p1 = p0 + 98304;     // +393216 floats
    float* base = attn + (size_t)row * 4096;
    int tid = threadIdx.x;             // 0..1023
    int w = tid >> 6;
    float4 a = p0[tid], c = p1[tid];
    float4 x;
    x.x = a.x + c.x; x.y = a.y + c.y;
    x.z = a.z + c.z; x.w = a.w + c.w;
    float m = fmaxf(fmaxf(x.x, x.y), fmaxf(x.z, x.w));
    m = waveReduceMax(m);
    if ((tid & 63) == 0) sh[w] = m;
    __syncthreads();
    float mm = sh[0];
#pragma unroll
    for (int i = 1; i < 16; ++i) mm = fmaxf(mm, sh[i]);
    x.x = expf(x.x - mm); x.y = expf(x.y - mm);
    x.z = expf(x.z - mm); x.w = expf(x.w - mm);
    float s = x.x + x.y + x.z + x.w;
    s = waveReduceSum(s);
    if ((tid & 63) == 0) sh[16 + w] = s;
    __syncthreads();
    float ss = sh[16];
#pragma unroll
    for (int i = 1; i < 16; ++i) ss += sh[16 + i];
    float inv = 1.0f / ss;
    x.x *= inv; x.y *= inv; x.z *= inv; x.w *= inv;
    reinterpret_cast<float4*>(base)[tid] = x;
}

// K5: ph partials. hidden loads lane-contiguous float4; attn values via 12
// readfirstlane-uniform scalar loads from the [96][4096] attn layout (walks
// sequentially in s -> each 64B scalar-cache line reused 16x).
__global__ __launch_bounds__(256) void k5_phpart(const float* __restrict__ hidden,
                                                 const float* __restrict__ attn,
                                                 float* __restrict__ php) {
    __shared__ float4 sh4[6 * 4 * 64];     // 24 KB
    int blk = blockIdx.x;              // 768 = 8 b * 3 ct * 32 sc
    int sc = blk & 31;
    int ct = (blk >> 5) % 3;
    int b = blk / 96;
    int tid = threadIdx.x;
    int w = tid >> 6, lane = tid & 63;
    int c = ct * 256 + lane * 4;
    int s0 = sc * 128 + w * 32;
    const float* hb = hidden + (size_t)(b * 4096 + s0) * 768 + c;
    float4 acc[12];
#pragma unroll
    for (int h = 0; h < 12; ++h) acc[h] = make_float4(0.f, 0.f, 0.f, 0.f);
#pragma unroll 4
    for (int g = 0; g < 32; ++g) {
        float4 x = *reinterpret_cast<const float4*>(hb + (size_t)g * 768);
        int aoff = __builtin_amdgcn_readfirstlane(b * 49152 + sc * 128 + (tid >> 6) * 32 + g);
        const float* ar = attn + aoff;
        float a[12];
#pragma unroll
        for (int h = 0; h < 12; ++h) a[h] = ar[(size_t)h * 4096];
#pragma unroll
        for (int h = 0; h < 12; ++h) {
            acc[h].x += a[h] * x.x; acc[h].y += a[h] * x.y;
            acc[h].z += a[h] * x.z; acc[h].w += a[h] * x.w;
        }
    }
    float* phpb = php + (size_t)(sc * 96 + b * 12) * 768 + ct * 256;
#pragma unroll
    for (int r = 0; r < 2; ++r) {
        if (r) __syncthreads();
#pragma unroll
        for (int i = 0; i < 6; ++i)
            sh4[(i * 4 + w) * 64 + lane] = acc[r * 6 + i];
        __syncthreads();
#pragma unroll
        for (int t = 0; t < 2; ++t) {
            int idx = t * 256 + tid;
            if (idx < 384) {
                int i = idx >> 6, l = idx & 63;
                float4 A = sh4[(i * 4 + 0) * 64 + l];
                float4 B = sh4[(i * 4 + 1) * 64 + l];
                float4 C = sh4[(i * 4 + 2) * 64 + l];
                float4 D = sh4[(i * 4 + 3) * 64 + l];
                float4 r4;
                r4.x = (A.x + B.x) + (C.x + D.x);
                r4.y = (A.y + B.y) + (C.y + D.y);
                r4.z = (A.z + B.z) + (C.z + D.z);
                r4.w = (A.w + B.w) + (C.w + D.w);
                *reinterpret_cast<float4*>(phpb + (size_t)(r * 6 + i) * 768 + l * 4) = r4;
            }
        }
    }
}

// K7: ctx_part[cch][b][j] = sum_{c in 32-chunk} ph[b,h(j),c] * Wv[c,j]
// ph reduced inline into LDS. Widened 144 -> 288 blocks.
__global__ __launch_bounds__(256) void k7_ctxpart(const float* __restrict__ Wv,
                                                  float* __restrict__ ws) {
    __shared__ float phl[256];         // [b][cc] for h=jt, 32-c chunk
    int blk = blockIdx.x;              // 288 = 12 jt * 24 cch
    int jt = blk % 12, cch = blk / 12;
    int tid = threadIdx.x;
    const float* php = ws + O_PHP;
    {
        int b = tid >> 5, cc = tid & 31;
        int c = cch * 32 + cc;
        const float* p = php + (size_t)(b * 12 + jt) * 768 + c;
        float s = 0.f;
#pragma unroll
        for (int sc = 0; sc < N_SC; ++sc) s += p[(size_t)sc * 73728];
        phl[tid] = s;
    }
    __syncthreads();
    int j = jt * 256 + tid;
    float acc[8];
#pragma unroll
    for (int b = 0; b < 8; ++b) acc[b] = 0.f;
    for (int cc = 0; cc < 32; ++cc) {
        int c = cch * 32 + cc;
        float wv = Wv[(size_t)c * 3072 + j];
#pragma unroll
        for (int b = 0; b < 8; ++b) acc[b] += phl[b * 32 + cc] * wv;
    }
#pragma unroll
    for (int b = 0; b < 8; ++b)
        ws[O_CTXP + (size_t)(cch * 8 + b) * 3072 + j] = acc[b];
}

// K8: out_part[ich][b][j] = sum_{i in 32-chunk} ctx[b][i]*Wp[i,j]
// ctx reduced inline into LDS. Widened 144 -> 288 blocks.
__global__ __launch_bounds__(256) void k8_outpart(const float* __restrict__ Wp,
                                                  const float* __restrict__ bv,
                                                  float* __restrict__ ws) {
    __shared__ float ctxl[256];        // [b][ii] for 32-i chunk
    int blk = blockIdx.x;              // 288 = 3 jt * 96 ich
    int jt = blk % 3, ich = blk / 3;
    int tid = threadIdx.x;
    {
        int b = tid >> 5, ii = tid & 31;
        int i = ich * 32 + ii;
        float s = bv[i];
#pragma unroll
        for (int cch = 0; cch < N_CCH; ++cch)
            s += ws[O_CTXP + (size_t)(cch * 8 + b) * 3072 + i];
        ctxl[tid] = s;
    }
    __syncthreads();
    int j = jt * 256 + tid;
    float acc[8];
#pragma unroll
    for (int b = 0; b < 8; ++b) acc[b] = 0.f;
    for (int ii = 0; ii < 32; ++ii) {
        int i = ich * 32 + ii;
        float wp = Wp[(size_t)i * 768 + j];
#pragma unroll
        for (int b = 0; b < 8; ++b) acc[b] += ctxl[b * 32 + ii] * wp;
    }
#pragma unroll
    for (int b = 0; b < 8; ++b)
        ws[O_OUTP + (size_t)(ich * 8 + b) * 768 + j] = acc[b];
}

// K9: reduce out partials + bp, layernorm. 768 threads, 1 col/thread.
__global__ __launch_bounds__(768) void k9_ln(const float* __restrict__ bp,
                                             const float* __restrict__ ln_w,
                                             const float* __restrict__ ln_b,
                                             const float* __restrict__ ws,
                                             float* __restrict__ pooled) {
    __shared__ float sh[24];           // [0..11] sum, [12..23] sumsq
    int b = blockIdx.x;
    int tid = threadIdx.x;             // 0..767 -> j
    int w = tid >> 6;
    const float* op = ws + O_OUTP;
    float v = bp[tid];
#pragma unroll
    for (int ich = 0; ich < N_ICH; ++ich) v += op[(size_t)(ich * 8 + b) * 768 + tid];
    float lsum = waveReduceSum(v);
    float lsq = waveReduceSum(v * v);
    if ((tid & 63) == 0) { sh[w] = lsum; sh[12 + w] = lsq; }
    __syncthreads();
    float tsum = 0.f, tsq = 0.f;
#pragma unroll
    for (int i = 0; i < 12; ++i) { tsum += sh[i]; tsq += sh[12 + i]; }
    float mean = tsum * (1.f / 768.f);
    float var = tsq * (1.f / 768.f) - mean * mean;
    float inv = rsqrtf(var + LN_EPS);
    pooled[b * 768 + tid] = (v - mean) * inv * (ln_w[tid] + 1.f) + ln_b[tid];
}

extern "C" void kernel_launch(void* const* d_in, const int* in_sizes, int n_in,
                              void* d_out, int out_size, void* d_ws, size_t ws_size,
                              hipStream_t stream) {
    const float* hidden = (const float*)d_in[0];
    const float* pq     = (const float*)d_in[1];
    const float* Wq     = (const float*)d_in[2];
    const float* bq     = (const float*)d_in[3];
    const float* Wk     = (const float*)d_in[4];
    const float* Wv     = (const float*)d_in[6];
    const float* bv     = (const float*)d_in[7];
    const float* Wp     = (const float*)d_in[8];
    const float* bp     = (const float*)d_in[9];
    const float* pds    = (const float*)d_in[10];
    const float* ln_w   = (const float*)d_in[11];
    const float* ln_b   = (const float*)d_in[12];
    float* out = (float*)d_out;
    float* ws  = (float*)d_ws;
    float* pooled = out;          // (8,1,768) = 6144 floats
    float* attn   = out + 6144;   // (8,12,1,4096) = 393216 floats

    k1a_qpart  <<<768, 256, 0, stream>>>(pq, Wq, ws);
    k1b_qreduce<<<12, 256, 0, stream>>>(bq, pds, ws);
    k2_wkeff   <<<768, 256, 0, stream>>>(Wk, ws);
    k3_logits  <<<1024, 256, 0, stream>>>(hidden, ws + O_WK, ws + O_PLOG);
    k4_softmax <<<96, 1024, 0, stream>>>(ws, attn);
    k5_phpart  <<<768, 256, 0, stream>>>(hidden, attn, ws + O_PHP);
    k7_ctxpart <<<288, 256, 0, stream>>>(Wv, ws);
    k8_outpart <<<288, 256, 0, stream>>>(Wp, bv, ws);
    k9_ln      <<<8, 768, 0, stream>>>(bp, ln_w, ln_b, ws, pooled);
}

// Round 6
// 253.935 us; speedup vs baseline: 1.0357x; 1.0357x over previous
//
#include <hip/hip_runtime.h>
#include <cstdint>
#include <cmath>

#define LN_EPS 1e-6f

// ---- workspace layout (float offsets) ----
#define O_QP    0u                     // qpart [16][3072]
#define O_Q     73728u                 // [3072] scaled q
#define O_WK    76800u                 // wk_eff [768][12]
#define O_PLOG  86016u                 // partial logits [2][96][4096]
#define O_PHP   1658880u               // ph partials [32][96][768]
#define N_SC    32
#define O_CTXP  4091904u               // ctx partials [12][8][3072]
#define N_CCH   12
#define O_OUTP  4411392u               // out partials [48][8][768]
#define N_ICH   48
#define O_ATT   4706304u               // attn_t [8][4096][16] (h-major, padded 12->16)

__device__ __forceinline__ float waveReduceSum(float v) {
#pragma unroll
    for (int o = 32; o >= 1; o >>= 1) v += __shfl_xor(v, o, 64);
    return v;
}
__device__ __forceinline__ float waveReduceMax(float v) {
#pragma unroll
    for (int o = 32; o >= 1; o >>= 1) v = fmaxf(v, __shfl_xor(v, o, 64));
    return v;
}

// Workgroup barrier without vmcnt drain (LDS visibility only).
__device__ __forceinline__ void block_sync_lds() {
    asm volatile("s_waitcnt lgkmcnt(0)" ::: "memory");
    __builtin_amdgcn_s_barrier();
    asm volatile("" ::: "memory");
}

// K1a: qpart[16][3072] over 768 blocks (48 col-tiles x 16 row-groups of 48 rows).
__global__ __launch_bounds__(256) void k1a_qpart(const float* __restrict__ pq,
                                                 const float* __restrict__ Wq,
                                                 float* __restrict__ ws) {
    __shared__ float sh[4][64];
    int bid = blockIdx.x;              // 768
    int ctile = bid % 48, rg = bid / 48;
    int tid = threadIdx.x;
    int l = tid & 63, sub = tid >> 6;
    int col = ctile * 64 + l;
    const float* wq = Wq + (size_t)(rg * 48 + sub * 12) * 3072 + col;
    const float* pr = pq + rg * 48 + sub * 12;
    float acc = 0.f;
#pragma unroll
    for (int i = 0; i < 12; ++i) acc += pr[i] * wq[(size_t)i * 3072];
    sh[sub][l] = acc;
    __syncthreads();
    if (tid < 64) {
        int c2 = ctile * 64 + tid;
        ws[O_QP + rg * 3072 + c2] = sh[0][tid] + sh[1][tid] + sh[2][tid] + sh[3][tid];
    }
}

// K1b: reduce 16 qparts + bias + softplus scale (12 blocks).
__global__ __launch_bounds__(256) void k1b_qreduce(const float* __restrict__ bq,
                                                   const float* __restrict__ pds,
                                                   float* __restrict__ ws) {
    int j = blockIdx.x * 256 + threadIdx.x;   // < 3072
    float a = bq[j];
#pragma unroll
    for (int rg = 0; rg < 16; ++rg) a += ws[O_QP + rg * 3072 + j];
    float x = pds[j & 255];
    float sp = (x > 20.f) ? x : log1pf(expf(x));
    ws[O_Q + j] = a * (1.442695041f / 16.0f) * sp;
}

// K2: wk_eff[c][h] = sum_d Wk[c, h*256+d]*q[h,d]
// (bk folds to a per-row softmax-invariant constant -> dropped)
__global__ __launch_bounds__(256) void k2_wkeff(const float* __restrict__ Wk,
                                                float* __restrict__ ws) {
    int c = blockIdx.x;                // 768
    int tid = threadIdx.x;
    int w = tid >> 6, lane = tid & 63;
    const float4* wk = reinterpret_cast<const float4*>(Wk + (size_t)c * 3072);
    const float4* qv = reinterpret_cast<const float4*>(ws + O_Q);
#pragma unroll
    for (int i = 0; i < 3; ++i) {
        int h = w * 3 + i;
        float4 a = wk[h * 64 + lane];
        float4 b = qv[h * 64 + lane];
        float d = a.x * b.x + a.y * b.y + a.z * b.z + a.w * b.w;
        d = waveReduceSum(d);
        if (lane == 0) ws[O_WK + c * 12 + h] = d;
    }
}

// K3: partial logits. block = (b, s-tile of 64 rows, c-HALF of 384).
// 8 chunks of 48 c, depth-2 register prefetch, raw-barrier sync (no vmcnt drain),
// wk via readfirstlane-uniform scalar loads. Verified round 2.
__global__ __launch_bounds__(256) void k3_logits(const float* __restrict__ hidden,
                                                 const float* __restrict__ wk,
                                                 float* __restrict__ plog) {
    __shared__ float4 tile4[2][768];   // 2 x 12 KB: [buf][r*12 + (j^(r&3))]
    int blk = blockIdx.x;              // 1024 = 8 b * 64 stiles * 2 halves
    int q2 = blk & 1;
    int st = (blk >> 1) & 63;
    int b = blk >> 7;
    int s0 = st * 64;
    const float* hb = hidden + (size_t)(b * 4096 + s0) * 768 + q2 * 384;
    int tid = threadIdx.x;
    int w = tid >> 6, lane = tid & 63;
    int rr[3], jj[3];
#pragma unroll
    for (int t = 0; t < 3; ++t) {
        int idx = t * 256 + tid;       // < 768
        rr[t] = idx / 12;
        jj[t] = idx % 12;
    }
    float4 v0[3], v1[3];
#pragma unroll
    for (int t = 0; t < 3; ++t)
        v0[t] = *reinterpret_cast<const float4*>(hb + rr[t] * 768 + jj[t] * 4);
#pragma unroll
    for (int t = 0; t < 3; ++t)
        v1[t] = *reinterpret_cast<const float4*>(hb + rr[t] * 768 + 48 + jj[t] * 4);

    float acc[12];
#pragma unroll
    for (int h = 0; h < 12; ++h) acc[h] = 0.f;

    auto step = [&](float4 (&v)[3], float4* buf, int ck) {
#pragma unroll
        for (int t = 0; t < 3; ++t)
            buf[rr[t] * 12 + (jj[t] ^ (rr[t] & 3))] = v[t];
        if (ck < 6) {
#pragma unroll
            for (int t = 0; t < 3; ++t)
                v[t] = *reinterpret_cast<const float4*>(hb + rr[t] * 768 + (ck + 2) * 48 + jj[t] * 4);
        }
        int wkoff = __builtin_amdgcn_readfirstlane((q2 * 384 + ck * 48 + (tid >> 6) * 12) * 12);
        const float* wr = wk + wkoff;
        block_sync_lds();
#pragma unroll
        for (int j2 = 0; j2 < 3; ++j2) {
            int jcol = w * 3 + j2;
            float4 x = buf[lane * 12 + (jcol ^ (lane & 3))];
            const float* wv = wr + j2 * 48;     // 4 c x 12 h, uniform address
            float xc[4] = {x.x, x.y, x.z, x.w};
#pragma unroll
            for (int cc = 0; cc < 4; ++cc) {
                const float* wc = wv + cc * 12;
#pragma unroll
                for (int h = 0; h < 12; ++h)
                    acc[h] += xc[cc] * wc[h];
            }
        }
    };
#pragma unroll
    for (int ck2 = 0; ck2 < 8; ck2 += 2) {
        step(v0, tile4[0], ck2);
        step(v1, tile4[1], ck2 + 1);
    }
    float* red = reinterpret_cast<float*>(tile4);
#pragma unroll
    for (int h = 0; h < 12; ++h) red[(w * 12 + h) * 64 + lane] = acc[h];
    __syncthreads();
    for (int idx = tid; idx < 768; idx += 256) {
        int h = idx / 64, r2 = idx & 63;
        float vv = red[(0 + h) * 64 + r2] + red[(12 + h) * 64 + r2] +
                   red[(24 + h) * 64 + r2] + red[(36 + h) * 64 + r2];
        plog[(size_t)q2 * 393216 + (size_t)(b * 12 + h) * 4096 + s0 + r2] = vv;
    }
}

// K4: softmax over s=4096, 1024 threads/block (1 float4 per thread).
// CHANGE vs round 4: grid remapped so all 12 h-blocks of one b are congruent
// mod 8 -> land on the SAME XCD (round-robin heuristic). Their 4B attn_t
// writes into shared 64B lines then merge in that XCD's L2 instead of
// partial-line thrashing across 8 non-coherent L2s (~30MB excess WRITE_SIZE
// seen in the mega-round profile).
__global__ __launch_bounds__(1024) void k4_softmax(const float* __restrict__ ws,
                                                   float* __restrict__ attn,
                                                   float* __restrict__ attn_t) {
    __shared__ float sh[32];           // [0..15] max, [16..31] sum
    int blk = blockIdx.x;              // 96
    int b = blk & 7, h = blk >> 3;     // same-b blocks: bid % 8 == b -> same XCD
    int row = b * 12 + h;
    const float4* p0 = reinterpret_cast<const float4*>(ws + O_PLOG + (size_t)row * 4096);
    const float4* p1 = p0 + 98304;     // +393216 floats
    float* base = attn + (size_t)row * 4096;
    float* at = attn_t + (size_t)b * 65536 + h;   // [s][16]
    int tid = threadIdx.x;             // 0..1023
    int w = tid >> 6;
    float4 a = p0[tid], c = p1[tid];
    float4 x;
    x.x = a.x + c.x; x.y = a.y + c.y;
    x.z = a.z + c.z; x.w = a.w + c.w;
    float m = fmaxf(fmaxf(x.x, x.y), fmaxf(x.z, x.w));
    m = waveReduceMax(m);
    if ((tid & 63) == 0) sh[w] = m;
    __syncthreads();
    float mm = sh[0];
#pragma unroll
    for (int i = 1; i < 16; ++i) mm = fmaxf(mm, sh[i]);
    x.x = expf(x.x - mm); x.y = expf(x.y - mm);
    x.z = expf(x.z - mm); x.w = expf(x.w - mm);
    float s = x.x + x.y + x.z + x.w;
    s = waveReduceSum(s);
    if ((tid & 63) == 0) sh[16 + w] = s;
    __syncthreads();
    float ss = sh[16];
#pragma unroll
    for (int i = 1; i < 16; ++i) ss += sh[16 + i];
    float inv = 1.0f / ss;
    x.x *= inv; x.y *= inv; x.z *= inv; x.w *= inv;
    reinterpret_cast<float4*>(base)[tid] = x;
    int sb = tid * 4;
    at[(size_t)(sb + 0) * 16] = x.x;
    at[(size_t)(sb + 1) * 16] = x.y;
    at[(size_t)(sb + 2) * 16] = x.z;
    at[(size_t)(sb + 3) * 16] = x.w;
}

// K5: ph partials. hidden loads lane-contiguous float4; attn via ONE uniform
// 48B load per s from attn_t (readfirstlane -> s_load). Verified round 4.
__global__ __launch_bounds__(256) void k5_phpart(const float* __restrict__ hidden,
                                                 const float* __restrict__ attn_t,
                                                 float* __restrict__ php) {
    __shared__ float4 sh4[6 * 4 * 64];     // 24 KB
    int blk = blockIdx.x;              // 768 = 8 b * 3 ct * 32 sc
    int sc = blk & 31;
    int ct = (blk >> 5) % 3;
    int b = blk / 96;
    int tid = threadIdx.x;
    int w = tid >> 6, lane = tid & 63;
    int c = ct * 256 + lane * 4;
    int s0 = sc * 128 + w * 32;
    const float* hb = hidden + (size_t)(b * 4096 + s0) * 768 + c;
    float4 acc[12];
#pragma unroll
    for (int h = 0; h < 12; ++h) acc[h] = make_float4(0.f, 0.f, 0.f, 0.f);
#pragma unroll 4
    for (int g = 0; g < 32; ++g) {
        float4 x = *reinterpret_cast<const float4*>(hb + (size_t)g * 768);
        int aoff = __builtin_amdgcn_readfirstlane((b * 4096 + sc * 128 + (tid >> 6) * 32 + g) * 16);
        const float* ar = attn_t + aoff;
        float a[12];
#pragma unroll
        for (int h = 0; h < 12; ++h) a[h] = ar[h];
#pragma unroll
        for (int h = 0; h < 12; ++h) {
            acc[h].x += a[h] * x.x; acc[h].y += a[h] * x.y;
            acc[h].z += a[h] * x.z; acc[h].w += a[h] * x.w;
        }
    }
    float* phpb = php + (size_t)(sc * 96 + b * 12) * 768 + ct * 256;
#pragma unroll
    for (int r = 0; r < 2; ++r) {
        if (r) __syncthreads();
#pragma unroll
        for (int i = 0; i < 6; ++i)
            sh4[(i * 4 + w) * 64 + lane] = acc[r * 6 + i];
        __syncthreads();
#pragma unroll
        for (int t = 0; t < 2; ++t) {
            int idx = t * 256 + tid;
            if (idx < 384) {
                int i = idx >> 6, l = idx & 63;
                float4 A = sh4[(i * 4 + 0) * 64 + l];
                float4 B = sh4[(i * 4 + 1) * 64 + l];
                float4 C = sh4[(i * 4 + 2) * 64 + l];
                float4 D = sh4[(i * 4 + 3) * 64 + l];
                float4 r4;
                r4.x = (A.x + B.x) + (C.x + D.x);
                r4.y = (A.y + B.y) + (C.y + D.y);
                r4.z = (A.z + B.z) + (C.z + D.z);
                r4.w = (A.w + B.w) + (C.w + D.w);
                *reinterpret_cast<float4*>(phpb + (size_t)(r * 6 + i) * 768 + l * 4) = r4;
            }
        }
    }
}

// K7: ctx_part[cch][b][j] = sum_{c in chunk} ph[b,h(j),c] * Wv[c,j]
// where ph[b,h,c] = sum_sc php[sc][b*12+h][c] is reduced inline into LDS.
__global__ __launch_bounds__(256) void k7_ctxpart(const float* __restrict__ Wv,
                                                  float* __restrict__ ws) {
    __shared__ float phl[512];         // [b][cc] for h=jt, c-chunk
    int blk = blockIdx.x;              // 144 = 12 jt * 12 cch
    int jt = blk % 12, cch = blk / 12;
    int tid = threadIdx.x;
    const float* php = ws + O_PHP;
#pragma unroll
    for (int t = 0; t < 2; ++t) {
        int idx = t * 256 + tid;       // < 512
        int b = idx >> 6, cc = idx & 63;
        int c = cch * 64 + cc;
        const float* p = php + (size_t)(b * 12 + jt) * 768 + c;
        float s = 0.f;
#pragma unroll
        for (int sc = 0; sc < N_SC; ++sc) s += p[(size_t)sc * 73728];
        phl[idx] = s;
    }
    __syncthreads();
    int j = jt * 256 + tid;
    float acc[8];
#pragma unroll
    for (int b = 0; b < 8; ++b) acc[b] = 0.f;
    for (int cc = 0; cc < 64; ++cc) {
        int c = cch * 64 + cc;
        float wv = Wv[(size_t)c * 3072 + j];
#pragma unroll
        for (int b = 0; b < 8; ++b) acc[b] += phl[b * 64 + cc] * wv;
    }
#pragma unroll
    for (int b = 0; b < 8; ++b)
        ws[O_CTXP + (size_t)(cch * 8 + b) * 3072 + j] = acc[b];
}

// K8: out_part[ich][b][j] = sum_{i in chunk} ctx[b][i]*Wp[i,j]
// where ctx[b][i] = bv[i] + sum_cch ctxp[cch][b][i] is reduced inline into LDS.
__global__ __launch_bounds__(256) void k8_outpart(const float* __restrict__ Wp,
                                                  const float* __restrict__ bv,
                                                  float* __restrict__ ws) {
    __shared__ float ctxl[512];        // [b][ii] for i-chunk
    int blk = blockIdx.x;              // 144 = 3 jt * 48 ich
    int jt = blk % 3, ich = blk / 3;
    int tid = threadIdx.x;
#pragma unroll
    for (int t = 0; t < 2; ++t) {
        int idx = t * 256 + tid;       // < 512
        int b = idx >> 6, ii = idx & 63;
        int i = ich * 64 + ii;
        float s = bv[i];
#pragma unroll
        for (int cch = 0; cch < N_CCH; ++cch)
            s += ws[O_CTXP + (size_t)(cch * 8 + b) * 3072 + i];
        ctxl[idx] = s;
    }
    __syncthreads();
    int j = jt * 256 + tid;
    float acc[8];
#pragma unroll
    for (int b = 0; b < 8; ++b) acc[b] = 0.f;
    for (int ii = 0; ii < 64; ++ii) {
        int i = ich * 64 + ii;
        float wp = Wp[(size_t)i * 768 + j];
#pragma unroll
        for (int b = 0; b < 8; ++b) acc[b] += ctxl[b * 64 + ii] * wp;
    }
#pragma unroll
    for (int b = 0; b < 8; ++b)
        ws[O_OUTP + (size_t)(ich * 8 + b) * 768 + j] = acc[b];
}

// K9: reduce out partials + bp, layernorm. 768 threads, 1 col/thread.
__global__ __launch_bounds__(768) void k9_ln(const float* __restrict__ bp,
                                             const float* __restrict__ ln_w,
                                             const float* __restrict__ ln_b,
                                             const float* __restrict__ ws,
                                             float* __restrict__ pooled) {
    __shared__ float sh[24];           // [0..11] sum, [12..23] sumsq
    int b = blockIdx.x;
    int tid = threadIdx.x;             // 0..767 -> j
    int w = tid >> 6;
    const float* op = ws + O_OUTP;
    float v = bp[tid];
#pragma unroll
    for (int ich = 0; ich < N_ICH; ++ich) v += op[(size_t)(ich * 8 + b) * 768 + tid];
    float lsum = waveReduceSum(v);
    float lsq = waveReduceSum(v * v);
    if ((tid & 63) == 0) { sh[w] = lsum; sh[12 + w] = lsq; }
    __syncthreads();
    float tsum = 0.f, tsq = 0.f;
#pragma unroll
    for (int i = 0; i < 12; ++i) { tsum += sh[i]; tsq += sh[12 + i]; }
    float mean = tsum * (1.f / 768.f);
    float var = tsq * (1.f / 768.f) - mean * mean;
    float inv = rsqrtf(var + LN_EPS);
    pooled[b * 768 + tid] = (v - mean) * inv * (ln_w[tid] + 1.f) + ln_b[tid];
}

extern "C" void kernel_launch(void* const* d_in, const int* in_sizes, int n_in,
                              void* d_out, int out_size, void* d_ws, size_t ws_size,
                              hipStream_t stream) {
    const float* hidden = (const float*)d_in[0];
    const float* pq     = (const float*)d_in[1];
    const float* Wq     = (const float*)d_in[2];
    const float* bq     = (const float*)d_in[3];
    const float* Wk     = (const float*)d_in[4];
    const float* Wv     = (const float*)d_in[6];
    const float* bv     = (const float*)d_in[7];
    const float* Wp     = (const float*)d_in[8];
    const float* bp     = (const float*)d_in[9];
    const float* pds    = (const float*)d_in[10];
    const float* ln_w   = (const float*)d_in[11];
    const float* ln_b   = (const float*)d_in[12];
    float* out = (float*)d_out;
    float* ws  = (float*)d_ws;
    float* pooled = out;          // (8,1,768) = 6144 floats
    float* attn   = out + 6144;   // (8,12,1,4096) = 393216 floats

    k1a_qpart  <<<768, 256, 0, stream>>>(pq, Wq, ws);
    k1b_qreduce<<<12, 256, 0, stream>>>(bq, pds, ws);
    k2_wkeff   <<<768, 256, 0, stream>>>(Wk, ws);
    k3_logits  <<<1024, 256, 0, stream>>>(hidden, ws + O_WK, ws + O_PLOG);
    k4_softmax <<<96, 1024, 0, stream>>>(ws, attn, ws + O_ATT);
    k5_phpart  <<<768, 256, 0, stream>>>(hidden, ws + O_ATT, ws + O_PHP);
    k7_ctxpart <<<144, 256, 0, stream>>>(Wv, ws);
    k8_outpart <<<144, 256, 0, stream>>>(Wp, bv, ws);
    k9_ln      <<<8, 768, 0, stream>>>(bp, ln_w, ln_b, ws, pooled);
}